// Round 9
// baseline (396.156 us; speedup 1.0000x reference)
//
#include <hip/hip_runtime.h>
#include <math.h>

#define TOKENS   8192
#define HIDDEN   7168
#define NEXPERT  256
#define NGROUP   8
#define TOPKG    4
#define TOPK     8
#define SCALE    2.5f

// GEMM: 128x128 block, BK=32, split-K 8 via atomicAdd into d_out.
// R9: single-buffered LDS (40 KB) + grid 1024 -> 3 blocks/CU resident
// (12 waves/CU). R8 proved depth-2 prefetch is useless at 2 blocks/CU:
// the limiter was occupancy (19%), not load latency. m97-style 2-barrier
// K-loop relies on cross-block wave overlap (m114) to hide the stage stall.
#define BM 128
#define BN 128
#define BK 32
#define KSPLIT 8
#define KPB (HIDDEN / KSPLIT)   // 896
#define NT  (KPB / BK)          // 28

// LDS: 4 planes (Ah,Al,Bh,Bl), each 128 rows x 40 halves (32 k + 8 pad).
// Row stride 80 B: frag b128 reads 16B-aligned, bank starts {0,4,..,28}
// uniform -> pure 8-phase, no excess conflict; staging b64 writes uniform
// 4-way (= minimum phases). Total 4*10 KB = 40 KB -> 3 blocks/CU (120 KB).
#define RSTR  40
#define PLANE (BM * RSTR)       // 5120 halves = 10 KB

typedef _Float16 half8 __attribute__((ext_vector_type(8)));
typedef _Float16 half4 __attribute__((ext_vector_type(4)));
typedef float    floatx4 __attribute__((ext_vector_type(4)));

// fp32 -> fp16 hi/lo RNE split (identical math to R3-R8: absmax 0.0 proven)
__device__ __forceinline__ void cvt_store(_Float16* __restrict__ Hh,
                                          _Float16* __restrict__ Hl,
                                          int row, int k0, float4 v) {
    half4 h, l;
    h[0] = (_Float16)v.x; h[1] = (_Float16)v.y;
    h[2] = (_Float16)v.z; h[3] = (_Float16)v.w;
    l[0] = (_Float16)(v.x - (float)h[0]);
    l[1] = (_Float16)(v.y - (float)h[1]);
    l[2] = (_Float16)(v.z - (float)h[2]);
    l[3] = (_Float16)(v.w - (float)h[3]);
    const int a = row * RSTR + k0;
    *(half4*)&Hh[a] = h;
    *(half4*)&Hl[a] = l;
}

__global__ __launch_bounds__(256) void zero_kernel(float* __restrict__ O) {
    const int i = blockIdx.x * 256 + threadIdx.x;
    *(float4*)&O[(size_t)i * 4] = float4{0.f, 0.f, 0.f, 0.f};
}

// ---------------------------------------------------------------------------
// Gate GEMM via fp16-split 3-product MFMA (bit-exact through routing):
//   x = xh + xl (fp16 RNE), logit = sum xh*wh + xh*wl + xl*wh  (fp32 acc)
// Single-buffered LDS, 2 barriers/tile, depth-1 register prefetch;
// atomicAdd epilogue (R3/R7: write traffic = 4 B per atomic, benign).
// ---------------------------------------------------------------------------
__global__ __launch_bounds__(256, 3) void gate_gemm_kernel(
    const float* __restrict__ X, const float* __restrict__ W,
    float* __restrict__ OUT)
{
    __shared__ _Float16 S[4 * PLANE];   // 40 KB
    _Float16* __restrict__ Ah = S;
    _Float16* __restrict__ Al = S + PLANE;
    _Float16* __restrict__ Bh = S + 2 * PLANE;
    _Float16* __restrict__ Bl = S + 3 * PLANE;

    const int tid = threadIdx.x;
    const int nb  = blockIdx.x * BN;
    const int mb  = blockIdx.y * BM;
    const int kb  = blockIdx.z * KPB;

    // staging map: 128x32 fp32 tile = 1024 float4; thread takes rows
    // q*32 + (tid>>3), k0 = (tid&7)*4, q = 0..3
    const int srow = tid >> 3;            // 0..31 (+q*32)
    const int sk0  = (tid & 7) * 4;       // 0..28
    const float* Aptr = X + (size_t)(mb + srow) * HIDDEN + kb + sk0;
    const float* Bptr = W + (size_t)(nb + srow) * HIDDEN + kb + sk0;

    // 4 waves as 2x2; wave tile 64m x 64n; 4x4 16x16x32 frags per wave
    const int lane = tid & 63, wave = tid >> 6;
    const int wm = (wave >> 1) * 64, wn = (wave & 1) * 64;
    const int fr = lane & 15, quad = lane >> 4;

    floatx4 acc[4][4];
#pragma unroll
    for (int i = 0; i < 4; i++)
#pragma unroll
        for (int j = 0; j < 4; j++) acc[i][j] = floatx4{0.f, 0.f, 0.f, 0.f};

    float4 av[4], bv[4];   // depth-1 prefetch (32 VGPR)

    auto load_tile = [&](int t) {
        const int o = t * BK;
#pragma unroll
        for (int q = 0; q < 4; q++) {
            av[q] = *(const float4*)(Aptr + o + (size_t)(q * 32) * HIDDEN);
            bv[q] = *(const float4*)(Bptr + o + (size_t)(q * 32) * HIDDEN);
        }
    };
    auto stage = [&]() {
#pragma unroll
        for (int q = 0; q < 4; q++) {
            cvt_store(Ah, Al, q * 32 + srow, sk0, av[q]);
            cvt_store(Bh, Bl, q * 32 + srow, sk0, bv[q]);
        }
    };
    auto compute = [&]() {
        half8 ah[4], al[4];
#pragma unroll
        for (int i = 0; i < 4; i++) {
            const int a = (wm + i * 16 + fr) * RSTR + quad * 8;
            ah[i] = *(const half8*)&Ah[a];
            al[i] = *(const half8*)&Al[a];
        }
#pragma unroll
        for (int j = 0; j < 4; j++) {
            const int b = (wn + j * 16 + fr) * RSTR + quad * 8;
            const half8 bh = *(const half8*)&Bh[b];
            const half8 bl = *(const half8*)&Bl[b];
#pragma unroll
            for (int i = 0; i < 4; i++) {
                acc[i][j] = __builtin_amdgcn_mfma_f32_16x16x32_f16(
                    al[i], bh, acc[i][j], 0, 0, 0);
                acc[i][j] = __builtin_amdgcn_mfma_f32_16x16x32_f16(
                    ah[i], bl, acc[i][j], 0, 0, 0);
                acc[i][j] = __builtin_amdgcn_mfma_f32_16x16x32_f16(
                    ah[i], bh, acc[i][j], 0, 0, 0);
            }
        }
    };

    load_tile(0);
    stage();                       // no prior readers; no barrier needed

#pragma unroll 1
    for (int t = 0; t < NT; t++) {
        __syncthreads();           // staged tile visible
        if (t + 1 < NT) load_tile(t + 1);   // issue early; MFMA hides latency
        compute();
        __syncthreads();           // all frag reads done before restage
        if (t + 1 < NT) stage();
    }

    // epilogue: D row = token (quad*4+reg), col = expert (lane&15);
    // split-K accumulation via atomicAdd
#pragma unroll
    for (int i = 0; i < 4; i++)
#pragma unroll
        for (int j = 0; j < 4; j++) {
            const int col = nb + wn + j * 16 + fr;
#pragma unroll
            for (int r = 0; r < 4; r++) {
                const int row = mb + wm + i * 16 + quad * 4 + r;
                atomicAdd(&OUT[(size_t)row * NEXPERT + col], acc[i][j][r]);
            }
        }
}

// ---------------------------------------------------------------------------
// Routing: one wave per token, in-place on d_out (logits -> gate weights).
// Sigmoid fused; exact jax semantics incl. lowest-index tie-breaks.
// ---------------------------------------------------------------------------
__global__ __launch_bounds__(256) void route_kernel(
    float* __restrict__ S, const float* __restrict__ bias)
{
    const int lane = threadIdx.x & 63;
    const int wave = threadIdx.x >> 6;
    const int t    = blockIdx.x * 4 + wave;

    const float4 lg4 = *(const float4*)&S[(size_t)t * NEXPERT + lane * 4];
    const float4 b4  = *(const float4*)&bias[lane * 4];
    float sc[4];
    sc[0] = 1.0f / (1.0f + expf(-lg4.x));
    sc[1] = 1.0f / (1.0f + expf(-lg4.y));
    sc[2] = 1.0f / (1.0f + expf(-lg4.z));
    sc[3] = 1.0f / (1.0f + expf(-lg4.w));
    float swb[4] = { sc[0] + b4.x, sc[1] + b4.y, sc[2] + b4.z, sc[3] + b4.w };

    // per-lane top-2 of 4
    float m1 = -INFINITY, m2 = -INFINITY;
#pragma unroll
    for (int j = 0; j < 4; j++) {
        const float v = swb[j];
        if (v > m1)      { m2 = m1; m1 = v; }
        else if (v > m2) { m2 = v; }
    }
    // merge across the 8 lanes of my group
#pragma unroll
    for (int s = 1; s < 8; s <<= 1) {
        const float o1 = __shfl_xor(m1, s, 64);
        const float o2 = __shfl_xor(m2, s, 64);
        const float hi = fmaxf(m1, o1);
        const float lo = fminf(m1, o1);
        m2 = fmaxf(lo, fmaxf(m2, o2));
        m1 = hi;
    }
    const float gs = m1 + m2;

    // top-4 groups by rank (tie -> lower group index)
    float gsc[NGROUP];
#pragma unroll
    for (int g = 0; g < NGROUP; g++) gsc[g] = __shfl(gs, g * 8, 64);
    const int myg = lane >> 3;
    int rank = 0;
#pragma unroll
    for (int g = 0; g < NGROUP; g++)
        rank += (gsc[g] > gs) || (gsc[g] == gs && g < myg);
    const bool kept = (rank < TOPKG);

    float v[4];
#pragma unroll
    for (int j = 0; j < 4; j++) v[j] = kept ? swb[j] : 0.0f;

    // top-8 experts: 8 rounds of wave argmax (lowest idx on ties)
    float sum = 0.0f;
    int selmask = 0;
    for (int r = 0; r < TOPK; r++) {
        float bv = -INFINITY;
        int   bi = 0x7fffffff;
#pragma unroll
        for (int j = 0; j < 4; j++) {
            const bool avail = ((selmask >> j) & 1) == 0;
            if (avail && v[j] > bv) { bv = v[j]; bi = lane * 4 + j; }
        }
#pragma unroll
        for (int s = 1; s < 64; s <<= 1) {
            const float ov = __shfl_xor(bv, s, 64);
            const int   oi = __shfl_xor(bi, s, 64);
            if (ov > bv || (ov == bv && oi < bi)) { bv = ov; bi = oi; }
        }
        const int wl = bi >> 2, wj = bi & 3;
        const float mysc = (wj == 0) ? sc[0] : (wj == 1) ? sc[1]
                         : (wj == 2) ? sc[2] : sc[3];
        sum += __shfl(mysc, wl, 64);
        if (lane == wl) selmask |= (1 << wj);
    }

    const float rcp = SCALE / (sum + 1e-20f);
    float4 o;
    o.x = (selmask & 1) ? sc[0] * rcp : 0.0f;
    o.y = (selmask & 2) ? sc[1] * rcp : 0.0f;
    o.z = (selmask & 4) ? sc[2] * rcp : 0.0f;
    o.w = (selmask & 8) ? sc[3] * rcp : 0.0f;
    *(float4*)&S[(size_t)t * NEXPERT + lane * 4] = o;
}

extern "C" void kernel_launch(void* const* d_in, const int* in_sizes, int n_in,
                              void* d_out, int out_size, void* d_ws, size_t ws_size,
                              hipStream_t stream) {
    const float* X    = (const float*)d_in[0];   // [8192, 7168]
    const float* W    = (const float*)d_in[1];   // [256, 7168]
    const float* bias = (const float*)d_in[2];   // [256]
    float* out = (float*)d_out;                  // [8192, 256]
    (void)d_ws; (void)ws_size;   // unused: harness poison-fill of d_ws is
                                 // fixed cost; reading d_ws adds writeback
                                 // traffic of displaced dirty poison lines

    zero_kernel<<<(TOKENS * NEXPERT / 4) / 256, 256, 0, stream>>>(out);
    dim3 ggrid(NEXPERT / BN, TOKENS / BM, KSPLIT);   // (2, 64, 8) = 1024 blocks
    gate_gemm_kernel<<<ggrid, 256, 0, stream>>>(X, W, out);
    route_kernel<<<TOKENS / 4, 256, 0, stream>>>(out, bias);
}